// Round 1
// baseline (17522.926 us; speedup 1.0000x reference)
//
#include <hip/hip_runtime.h>

#define TT 4096
#define HH 512
#define GG 2048      // 4*H
#define NSLICE 32    // workgroups per LSTM chain

__device__ __forceinline__ float sigm(float x) { return 1.0f / (1.0f + __expf(-x)); }
__device__ __forceinline__ float tanh_fast(float x) {
    x = fminf(20.0f, fmaxf(-20.0f, x));
    float e = __expf(2.0f * x);
    return (e - 1.0f) / (e + 1.0f);
}

// ---------------------------------------------------------------------------
// xw = relu([word_emb[w]; pos_emb[p]] @ W^T + b), W: [512, 332]
// 8 timesteps per block, 256 threads.
__global__ __launch_bounds__(256) void k_xw(
    const int* __restrict__ words, const int* __restrict__ pos,
    const float* __restrict__ wemb, const float* __restrict__ pemb,
    const float* __restrict__ W, const float* __restrict__ b,
    float* __restrict__ out)
{
    __shared__ float xr[8][336];
    const int t0 = blockIdx.x * 8, tid = threadIdx.x;
    for (int s = 0; s < 8; ++s) {
        int w = words[t0 + s], p = pos[t0 + s];
        for (int i = tid; i < 332; i += 256)
            xr[s][i] = (i < 300) ? wemb[(size_t)w * 300 + i] : pemb[p * 32 + (i - 300)];
    }
    __syncthreads();
    const int o1 = tid, o2 = tid + 256;
    float acc[8][2] = {};
    for (int k = 0; k < 332; ++k) {
        float wa = W[(size_t)o1 * 332 + k];
        float wb = W[(size_t)o2 * 332 + k];
#pragma unroll
        for (int s = 0; s < 8; ++s) {
            float x = xr[s][k];
            acc[s][0] += wa * x;
            acc[s][1] += wb * x;
        }
    }
#pragma unroll
    for (int s = 0; s < 8; ++s) {
        out[(size_t)(t0 + s) * 512 + o1] = fmaxf(acc[s][0] + b[o1], 0.0f);
        out[(size_t)(t0 + s) * 512 + o2] = fmaxf(acc[s][1] + b[o2], 0.0f);
    }
}

// xa = relu(act_emb[a] @ W^T + b), W: [512, 64]
__global__ __launch_bounds__(256) void k_xa(
    const int* __restrict__ acts, const float* __restrict__ aemb,
    const float* __restrict__ W, const float* __restrict__ b,
    float* __restrict__ out)
{
    __shared__ float xr[8][68];
    const int t0 = blockIdx.x * 8, tid = threadIdx.x;
    for (int s = 0; s < 8; ++s) {
        int a = acts[t0 + s];
        if (tid < 64) xr[s][tid] = aemb[(size_t)a * 64 + tid];
    }
    __syncthreads();
    const int o1 = tid, o2 = tid + 256;
    float acc[8][2] = {};
    for (int k = 0; k < 64; ++k) {
        float wa = W[(size_t)o1 * 64 + k];
        float wb = W[(size_t)o2 * 64 + k];
#pragma unroll
        for (int s = 0; s < 8; ++s) {
            float x = xr[s][k];
            acc[s][0] += wa * x;
            acc[s][1] += wb * x;
        }
    }
#pragma unroll
    for (int s = 0; s < 8; ++s) {
        out[(size_t)(t0 + s) * 512 + o1] = fmaxf(acc[s][0] + b[o1], 0.0f);
        out[(size_t)(t0 + s) * 512 + o2] = fmaxf(acc[s][1] + b[o2], 0.0f);
    }
}

// ---------------------------------------------------------------------------
// C[M,N] = A[M,K] * B[N,K]^T + b1[N] (+ b2[N]); op==1 -> tanh epilogue.
// 64x64 tile, BK=16, 256 threads, 4x4 per thread. M,N,K multiples of 64/64/16.
__global__ __launch_bounds__(256) void gemm_nt(
    const float* __restrict__ A, const float* __restrict__ B, float* __restrict__ C,
    const float* __restrict__ b1, const float* __restrict__ b2,
    int M, int N, int K, int op)
{
    __shared__ __align__(16) float As[16][68];
    __shared__ __align__(16) float Bs[16][68];
    const int tid = threadIdx.x;
    const int bm = blockIdx.y * 64, bn = blockIdx.x * 64;
    const int lr = tid >> 2, lc = tid & 3;
    const int tm = tid & 15, tn = tid >> 4;
    float acc[4][4] = {};
    for (int k0 = 0; k0 < K; k0 += 16) {
        float4 a4 = *(const float4*)(A + (size_t)(bm + lr) * K + k0 + lc * 4);
        float4 b4 = *(const float4*)(B + (size_t)(bn + lr) * K + k0 + lc * 4);
        As[lc * 4 + 0][lr] = a4.x; As[lc * 4 + 1][lr] = a4.y;
        As[lc * 4 + 2][lr] = a4.z; As[lc * 4 + 3][lr] = a4.w;
        Bs[lc * 4 + 0][lr] = b4.x; Bs[lc * 4 + 1][lr] = b4.y;
        Bs[lc * 4 + 2][lr] = b4.z; Bs[lc * 4 + 3][lr] = b4.w;
        __syncthreads();
#pragma unroll
        for (int k = 0; k < 16; ++k) {
            const float4 av = *(const float4*)&As[k][tm * 4];
            const float4 bv = *(const float4*)&Bs[k][tn * 4];
            acc[0][0] += av.x * bv.x; acc[0][1] += av.x * bv.y; acc[0][2] += av.x * bv.z; acc[0][3] += av.x * bv.w;
            acc[1][0] += av.y * bv.x; acc[1][1] += av.y * bv.y; acc[1][2] += av.y * bv.z; acc[1][3] += av.y * bv.w;
            acc[2][0] += av.z * bv.x; acc[2][1] += av.z * bv.y; acc[2][2] += av.z * bv.z; acc[2][3] += av.z * bv.w;
            acc[3][0] += av.w * bv.x; acc[3][1] += av.w * bv.y; acc[3][2] += av.w * bv.z; acc[3][3] += av.w * bv.w;
        }
        __syncthreads();
    }
#pragma unroll
    for (int i = 0; i < 4; ++i) {
        const int r = bm + tm * 4 + i;
#pragma unroll
        for (int j = 0; j < 4; ++j) {
            const int cc = bn + tn * 4 + j;
            float v = acc[i][j] + b1[cc];
            if (b2) v += b2[cc];
            if (op == 1) v = tanh_fast(v);
            C[(size_t)r * N + cc] = v;
        }
    }
}

// ---------------------------------------------------------------------------
// Sequential LSTM scan: 3 chains x 32 slices = 96 WGs of 256 threads.
// Each WG owns 16 output elements (= 64 gate rows) of one chain; whh rows live
// in registers (32 float4 per thread). h is exchanged via global memory with a
// per-chain monotonic-counter barrier (device-scope atomics + agent fences).
__global__ __launch_bounds__(256, 1) void scan_kernel(
    const float* __restrict__ gx,   // [3][T][2048], includes x-part + both biases
    const float* __restrict__ whh0, const float* __restrict__ whh1, const float* __restrict__ whh2,
    const float* __restrict__ h00, const float* __restrict__ h01, const float* __restrict__ h02,
    const float* __restrict__ c00, const float* __restrict__ c01, const float* __restrict__ c02,
    float* __restrict__ hbuf,       // [2][3][512] double buffer
    float* __restrict__ htop,       // [T][1536] pre-update h (stk|buf|hist)
    unsigned* __restrict__ counters)
{
    const int chain = blockIdx.x / NSLICE;
    const int slice = blockIdx.x % NSLICE;
    const int tid = threadIdx.x;
    const int q = tid >> 6;          // wave id = column chunk (128 cols)
    const int rl = tid & 63;         // local gate row
    const int row = (rl >> 4) * HH + slice * 16 + (rl & 15);  // global gate row

    const float* whh = (chain == 0) ? whh0 : (chain == 1) ? whh1 : whh2;
    const float* h0  = (chain == 0) ? h00  : (chain == 1) ? h01  : h02;
    const float* c0  = (chain == 0) ? c00  : (chain == 1) ? c01  : c02;
    const float* gxc = gx + (size_t)chain * TT * GG;
    unsigned* cnt = counters + chain * 64;

    // one-time: weight slice into registers (128 VGPRs)
    float4 w4[32];
    {
        const float4* wp = (const float4*)(whh + (size_t)row * HH + q * 128);
#pragma unroll
        for (int i = 0; i < 32; ++i) w4[i] = wp[i];
    }
    float c_reg = (tid < 16) ? c0[slice * 16 + tid] : 0.0f;

    __shared__ float h_lds[512];
    __shared__ float part[320];   // [64][5] padded

    for (int t = 0; t < TT; ++t) {
        const float* hsrc = (t == 0) ? h0 : (hbuf + ((size_t)(t & 1) * 3 + chain) * HH);
        float gxv = 0.0f;
        if (tid < 64) gxv = gxc[(size_t)t * GG + row];           // overlaps with LDS fill
        if (tid < 128) ((float4*)h_lds)[tid] = ((const float4*)hsrc)[tid];
        __syncthreads();

        // record pre-update h for the batched summary/log-softmax head
        if (tid < 16) htop[(size_t)t * 1536 + chain * HH + slice * 16 + tid] = h_lds[slice * 16 + tid];

        // partial dot: rows in registers, h broadcast from LDS
        float acc = 0.0f;
        {
            const float4* hq = (const float4*)(h_lds + q * 128);
#pragma unroll
            for (int i = 0; i < 32; ++i) {
                float4 hv = hq[i];
                acc += w4[i].x * hv.x; acc += w4[i].y * hv.y;
                acc += w4[i].z * hv.z; acc += w4[i].w * hv.w;
            }
        }
        part[rl * 5 + q] = acc;
        __syncthreads();

        if (tid < 64) {
            float gv = part[tid * 5 + 0] + part[tid * 5 + 1] + part[tid * 5 + 2] + part[tid * 5 + 3] + gxv;
            part[tid * 5 + 4] = gv;
        }
        __syncthreads();

        if (tid < 16) {
            float gi = part[tid * 5 + 4];
            float gf = part[(16 + tid) * 5 + 4];
            float gg = part[(32 + tid) * 5 + 4];
            float go = part[(48 + tid) * 5 + 4];
            float c2 = sigm(gf) * c_reg + sigm(gi) * tanh_fast(gg);
            float h2 = sigm(go) * tanh_fast(c2);
            c_reg = c2;
            hbuf[((size_t)((t + 1) & 1) * 3 + chain) * HH + slice * 16 + tid] = h2;
        }

        // per-chain barrier: release h2, wait for all 32 slices of this chain
        if (tid == 0) {
            __builtin_amdgcn_fence(__ATOMIC_RELEASE, "agent");
            __hip_atomic_fetch_add(cnt, 1u, __ATOMIC_RELAXED, __HIP_MEMORY_SCOPE_AGENT);
            const unsigned target = (unsigned)(t + 1) * NSLICE;
            while (__hip_atomic_load(cnt, __ATOMIC_RELAXED, __HIP_MEMORY_SCOPE_AGENT) < target)
                __builtin_amdgcn_s_sleep(2);
            __builtin_amdgcn_fence(__ATOMIC_ACQUIRE, "agent");
        }
        __syncthreads();
    }
}

// ---------------------------------------------------------------------------
// per-row logits + log_softmax: out[t] = log_softmax(summ[t] @ Wo^T + bo)
__global__ __launch_bounds__(128) void k_logp(
    const float* __restrict__ summ, const float* __restrict__ Wo,
    const float* __restrict__ bo, float* __restrict__ out)
{
    __shared__ float srow[512];
    __shared__ float z[104];
    __shared__ float red[2];
    const int t = blockIdx.x, tid = threadIdx.x;
    ((float4*)srow)[tid] = ((const float4*)(summ + (size_t)t * 512))[tid];
    __syncthreads();
    if (tid < 100) {
        float a = bo[tid];
        const float* wr = Wo + (size_t)tid * 512;
        for (int k = 0; k < 512; k += 4)
            a += wr[k] * srow[k] + wr[k + 1] * srow[k + 1] + wr[k + 2] * srow[k + 2] + wr[k + 3] * srow[k + 3];
        z[tid] = a;
    }
    __syncthreads();
    if (tid < 64) {
        float m = z[tid];
        if (tid + 64 < 100) m = fmaxf(m, z[tid + 64]);
#pragma unroll
        for (int off = 32; off >= 1; off >>= 1) m = fmaxf(m, __shfl_xor(m, off, 64));
        float e = __expf(z[tid] - m) + ((tid + 64 < 100) ? __expf(z[tid + 64] - m) : 0.0f);
#pragma unroll
        for (int off = 32; off >= 1; off >>= 1) e += __shfl_xor(e, off, 64);
        if (tid == 0) { red[0] = m; red[1] = __logf(e); }
    }
    __syncthreads();
    if (tid < 100) out[(size_t)t * 100 + tid] = z[tid] - red[0] - red[1];
}

// ---------------------------------------------------------------------------
extern "C" void kernel_launch(void* const* d_in, const int* in_sizes, int n_in,
                              void* d_out, int out_size, void* d_ws, size_t ws_size,
                              hipStream_t stream)
{
    const int* words = (const int*)d_in[0];
    const int* pos   = (const int*)d_in[1];
    const int* acts  = (const int*)d_in[2];
    const float* wemb  = (const float*)d_in[3];
    const float* pemb  = (const float*)d_in[4];
    const float* aemb  = (const float*)d_in[5];
    const float* w2e_w = (const float*)d_in[6];
    const float* w2e_b = (const float*)d_in[7];
    const float* a2e_w = (const float*)d_in[8];
    const float* a2e_b = (const float*)d_in[9];
    // stk: wih 10, whh 11, bih 12, bhh 13, h0 14, c0 15
    // buf: wih 16, whh 17, bih 18, bhh 19, h0 20, c0 21
    // hist: wih 22, whh 23, bih 24, bhh 25, h0 26, c0 27
    const float* sum_w = (const float*)d_in[28];
    const float* sum_b = (const float*)d_in[29];
    const float* out_w = (const float*)d_in[30];
    const float* out_b = (const float*)d_in[31];

    float* ws = (float*)d_ws;
    float* xw   = ws;                                   // [4096*512]
    float* xa   = xw + (size_t)TT * HH;                 // [4096*512]
    float* gxp  = xa + (size_t)TT * HH;                 // [3][4096][2048]
    float* htop = gxp + (size_t)3 * TT * GG;            // [4096][1536]
    float* hbuf = htop + (size_t)TT * 3 * HH;           // [2][3][512]
    unsigned* counters = (unsigned*)(hbuf + 2 * 3 * HH);// [3*64]
    float* summary = xw;                                // alias: xw dead after Gx GEMMs

    hipMemsetAsync(counters, 0, 3 * 64 * sizeof(unsigned), stream);

    // Phase A: input projections
    k_xw<<<dim3(TT / 8), dim3(256), 0, stream>>>(words, pos, wemb, pemb, w2e_w, w2e_b, xw);
    k_xa<<<dim3(TT / 8), dim3(256), 0, stream>>>(acts, aemb, a2e_w, a2e_b, xa);

    // Phase A: Gx[c] = x_c @ wih_c^T + (bih_c + bhh_c)
    dim3 g2(GG / 64, TT / 64);
    gemm_nt<<<g2, dim3(256), 0, stream>>>(xw, (const float*)d_in[10], gxp,
                                          (const float*)d_in[12], (const float*)d_in[13],
                                          TT, GG, HH, 0);
    gemm_nt<<<g2, dim3(256), 0, stream>>>(xw, (const float*)d_in[16], gxp + (size_t)TT * GG,
                                          (const float*)d_in[18], (const float*)d_in[19],
                                          TT, GG, HH, 0);
    gemm_nt<<<g2, dim3(256), 0, stream>>>(xa, (const float*)d_in[22], gxp + (size_t)2 * TT * GG,
                                          (const float*)d_in[24], (const float*)d_in[25],
                                          TT, GG, HH, 0);

    // Phase B: sequential scan (96 blocks << 256 CUs -> co-resident)
    scan_kernel<<<dim3(3 * NSLICE), dim3(256), 0, stream>>>(
        gxp,
        (const float*)d_in[11], (const float*)d_in[17], (const float*)d_in[23],
        (const float*)d_in[14], (const float*)d_in[20], (const float*)d_in[26],
        (const float*)d_in[15], (const float*)d_in[21], (const float*)d_in[27],
        hbuf, htop, counters);

    // Phase C: summary = tanh(Htop @ sum_w^T + sum_b); then logits + log_softmax
    dim3 g3(HH / 64, TT / 64);
    gemm_nt<<<g3, dim3(256), 0, stream>>>(htop, sum_w, summary, sum_b, nullptr,
                                          TT, HH, 3 * HH, 1);
    k_logp<<<dim3(TT), dim3(128), 0, stream>>>(summary, out_w, out_b, (float*)d_out);
}

// Round 2
// 9330.109 us; speedup vs baseline: 1.8781x; 1.8781x over previous
//
#include <hip/hip_runtime.h>
#include <stdint.h>

#define TT 4096
#define HH 512
#define GG 2048      // 4*H
#define NS 64        // workgroups (slices) per LSTM chain

typedef unsigned long long u64;

__device__ __forceinline__ float sigm(float x) { return 1.0f / (1.0f + __expf(-x)); }
__device__ __forceinline__ float tanh_fast(float x) {
    x = fminf(20.0f, fmaxf(-20.0f, x));
    float e = __expf(2.0f * x);
    return (e - 1.0f) / (e + 1.0f);
}

// ---------------------------------------------------------------------------
// xw = relu([word_emb[w]; pos_emb[p]] @ W^T + b), W: [512, 332]
__global__ __launch_bounds__(256) void k_xw(
    const int* __restrict__ words, const int* __restrict__ pos,
    const float* __restrict__ wemb, const float* __restrict__ pemb,
    const float* __restrict__ W, const float* __restrict__ b,
    float* __restrict__ out)
{
    __shared__ float xr[8][336];
    const int t0 = blockIdx.x * 8, tid = threadIdx.x;
    for (int s = 0; s < 8; ++s) {
        int w = words[t0 + s], p = pos[t0 + s];
        for (int i = tid; i < 332; i += 256)
            xr[s][i] = (i < 300) ? wemb[(size_t)w * 300 + i] : pemb[p * 32 + (i - 300)];
    }
    __syncthreads();
    const int o1 = tid, o2 = tid + 256;
    float acc[8][2] = {};
    for (int k = 0; k < 332; ++k) {
        float wa = W[(size_t)o1 * 332 + k];
        float wb = W[(size_t)o2 * 332 + k];
#pragma unroll
        for (int s = 0; s < 8; ++s) {
            float x = xr[s][k];
            acc[s][0] += wa * x;
            acc[s][1] += wb * x;
        }
    }
#pragma unroll
    for (int s = 0; s < 8; ++s) {
        out[(size_t)(t0 + s) * 512 + o1] = fmaxf(acc[s][0] + b[o1], 0.0f);
        out[(size_t)(t0 + s) * 512 + o2] = fmaxf(acc[s][1] + b[o2], 0.0f);
    }
}

// xa = relu(act_emb[a] @ W^T + b), W: [512, 64]
__global__ __launch_bounds__(256) void k_xa(
    const int* __restrict__ acts, const float* __restrict__ aemb,
    const float* __restrict__ W, const float* __restrict__ b,
    float* __restrict__ out)
{
    __shared__ float xr[8][68];
    const int t0 = blockIdx.x * 8, tid = threadIdx.x;
    for (int s = 0; s < 8; ++s) {
        int a = acts[t0 + s];
        if (tid < 64) xr[s][tid] = aemb[(size_t)a * 64 + tid];
    }
    __syncthreads();
    const int o1 = tid, o2 = tid + 256;
    float acc[8][2] = {};
    for (int k = 0; k < 64; ++k) {
        float wa = W[(size_t)o1 * 64 + k];
        float wb = W[(size_t)o2 * 64 + k];
#pragma unroll
        for (int s = 0; s < 8; ++s) {
            float x = xr[s][k];
            acc[s][0] += wa * x;
            acc[s][1] += wb * x;
        }
    }
#pragma unroll
    for (int s = 0; s < 8; ++s) {
        out[(size_t)(t0 + s) * 512 + o1] = fmaxf(acc[s][0] + b[o1], 0.0f);
        out[(size_t)(t0 + s) * 512 + o2] = fmaxf(acc[s][1] + b[o2], 0.0f);
    }
}

// ---------------------------------------------------------------------------
// C[M,N] = A[M,K] * B[N,K]^T + b1[N] (+ b2[N]); op==1 -> tanh epilogue.
__global__ __launch_bounds__(256) void gemm_nt(
    const float* __restrict__ A, const float* __restrict__ B, float* __restrict__ C,
    const float* __restrict__ b1, const float* __restrict__ b2,
    int M, int N, int K, int op)
{
    __shared__ __align__(16) float As[16][68];
    __shared__ __align__(16) float Bs[16][68];
    const int tid = threadIdx.x;
    const int bm = blockIdx.y * 64, bn = blockIdx.x * 64;
    const int lr = tid >> 2, lc = tid & 3;
    const int tm = tid & 15, tn = tid >> 4;
    float acc[4][4] = {};
    for (int k0 = 0; k0 < K; k0 += 16) {
        float4 a4 = *(const float4*)(A + (size_t)(bm + lr) * K + k0 + lc * 4);
        float4 b4 = *(const float4*)(B + (size_t)(bn + lr) * K + k0 + lc * 4);
        As[lc * 4 + 0][lr] = a4.x; As[lc * 4 + 1][lr] = a4.y;
        As[lc * 4 + 2][lr] = a4.z; As[lc * 4 + 3][lr] = a4.w;
        Bs[lc * 4 + 0][lr] = b4.x; Bs[lc * 4 + 1][lr] = b4.y;
        Bs[lc * 4 + 2][lr] = b4.z; Bs[lc * 4 + 3][lr] = b4.w;
        __syncthreads();
#pragma unroll
        for (int k = 0; k < 16; ++k) {
            const float4 av = *(const float4*)&As[k][tm * 4];
            const float4 bv = *(const float4*)&Bs[k][tn * 4];
            acc[0][0] += av.x * bv.x; acc[0][1] += av.x * bv.y; acc[0][2] += av.x * bv.z; acc[0][3] += av.x * bv.w;
            acc[1][0] += av.y * bv.x; acc[1][1] += av.y * bv.y; acc[1][2] += av.y * bv.z; acc[1][3] += av.y * bv.w;
            acc[2][0] += av.z * bv.x; acc[2][1] += av.z * bv.y; acc[2][2] += av.z * bv.z; acc[2][3] += av.z * bv.w;
            acc[3][0] += av.w * bv.x; acc[3][1] += av.w * bv.y; acc[3][2] += av.w * bv.z; acc[3][3] += av.w * bv.w;
        }
        __syncthreads();
    }
#pragma unroll
    for (int i = 0; i < 4; ++i) {
        const int r = bm + tm * 4 + i;
#pragma unroll
        for (int j = 0; j < 4; ++j) {
            const int cc = bn + tn * 4 + j;
            float v = acc[i][j] + b1[cc];
            if (b2) v += b2[cc];
            if (op == 1) v = tanh_fast(v);
            C[(size_t)r * N + cc] = v;
        }
    }
}

// ---------------------------------------------------------------------------
// Fence-free dataflow LSTM scan.
// 3 chains x 64 slices = 192 WGs of 256 threads. Each WG owns 8 h-outputs
// (32 gate rows); each thread holds a 64-col slice of one gate row in 16
// named float4 registers. h is exchanged as tagged (epoch<<32|f32) 8-byte
// atomic pairs at agent scope (L3-coherent, no fences, no barrier RMW).
// Ordering is self-enforcing: a slice cannot publish epoch t+1 until it has
// consumed ALL of epoch t, so the 2-slot buffer can never be overwritten
// while a reader still needs it.
#define LDW(i) const float4 w##i = wp[i];
#define DOT(i) { float4 hv = hq[i]; \
    acc = fmaf(w##i.x, hv.x, acc); acc = fmaf(w##i.y, hv.y, acc); \
    acc = fmaf(w##i.z, hv.z, acc); acc = fmaf(w##i.w, hv.w, acc); }

__global__ __launch_bounds__(256, 1) void scan_kernel(
    const float* __restrict__ gx,   // [3][T][2048] x-part + both biases
    const float* __restrict__ whh0, const float* __restrict__ whh1, const float* __restrict__ whh2,
    const float* __restrict__ h00, const float* __restrict__ h01, const float* __restrict__ h02,
    const float* __restrict__ c00, const float* __restrict__ c01, const float* __restrict__ c02,
    u64* __restrict__ hbuf,         // [2][3][512] tagged pairs, pre-zeroed
    float* __restrict__ htop)       // [T][1536] pre-update h (stk|buf|hist)
{
    const int chain = blockIdx.x / NS;
    const int slice = blockIdx.x % NS;
    const int tid = threadIdx.x;
    const int r = tid >> 3;          // local gate row 0..31
    const int k = tid & 7;           // 64-col chunk
    const int gate = r >> 3;         // 0..3 (i,f,g,o)
    const int j = r & 7;             // output index within slice
    const int grow = gate * HH + slice * 8 + j;

    const float* whh = (chain == 0) ? whh0 : (chain == 1) ? whh1 : whh2;
    const float* h0  = (chain == 0) ? h00  : (chain == 1) ? h01  : h02;
    const float* c0  = (chain == 0) ? c00  : (chain == 1) ? c01  : c02;
    const float* gxc = gx + (size_t)chain * TT * GG;

    // weight slice -> 16 named float4 (64 VGPRs, statically indexed)
    const float4* wp = (const float4*)(whh + (size_t)grow * HH + k * 64);
    LDW(0) LDW(1) LDW(2) LDW(3) LDW(4) LDW(5) LDW(6) LDW(7)
    LDW(8) LDW(9) LDW(10) LDW(11) LDW(12) LDW(13) LDW(14) LDW(15)

    float c_reg = 0.0f;
    if (tid < 8) {
        c_reg = c0[slice * 8 + tid];
        float hv = h0[slice * 8 + tid];
        u64 pv = ((u64)1u << 32) | (u64)__float_as_uint(hv);   // epoch 0 -> tag 1
        __hip_atomic_store(&hbuf[(size_t)chain * HH + slice * 8 + tid], pv,
                           __ATOMIC_RELAXED, __HIP_MEMORY_SCOPE_AGENT);
        htop[(size_t)chain * HH + slice * 8 + tid] = hv;       // htop[0]
    }

    __shared__ float h_lds[8 * 68];  // padded: chunk stride 68 floats (bank-spread)
    __shared__ float gsum[32];

    for (int t = 0; t < TT; ++t) {
        float gxv = 0.0f;
        if (k == 0) gxv = gxc[(size_t)t * GG + grow];   // issued early, hides under poll

        if (tid < 64) {
            const u64* src = hbuf + (size_t)((t & 1) * 3 + chain) * HH + tid * 8;
            const unsigned need = (unsigned)(t + 1);
            u64 p0, p1, p2, p3, p4, p5, p6, p7;
            for (;;) {
                p0 = __hip_atomic_load(src + 0, __ATOMIC_RELAXED, __HIP_MEMORY_SCOPE_AGENT);
                p1 = __hip_atomic_load(src + 1, __ATOMIC_RELAXED, __HIP_MEMORY_SCOPE_AGENT);
                p2 = __hip_atomic_load(src + 2, __ATOMIC_RELAXED, __HIP_MEMORY_SCOPE_AGENT);
                p3 = __hip_atomic_load(src + 3, __ATOMIC_RELAXED, __HIP_MEMORY_SCOPE_AGENT);
                p4 = __hip_atomic_load(src + 4, __ATOMIC_RELAXED, __HIP_MEMORY_SCOPE_AGENT);
                p5 = __hip_atomic_load(src + 5, __ATOMIC_RELAXED, __HIP_MEMORY_SCOPE_AGENT);
                p6 = __hip_atomic_load(src + 6, __ATOMIC_RELAXED, __HIP_MEMORY_SCOPE_AGENT);
                p7 = __hip_atomic_load(src + 7, __ATOMIC_RELAXED, __HIP_MEMORY_SCOPE_AGENT);
                int ok = (unsigned)(p0 >> 32) >= need && (unsigned)(p1 >> 32) >= need &&
                         (unsigned)(p2 >> 32) >= need && (unsigned)(p3 >> 32) >= need &&
                         (unsigned)(p4 >> 32) >= need && (unsigned)(p5 >> 32) >= need &&
                         (unsigned)(p6 >> 32) >= need && (unsigned)(p7 >> 32) >= need;
                if (__all(ok)) break;
                __builtin_amdgcn_s_sleep(1);
            }
            float4* d = (float4*)(h_lds + (tid >> 3) * 68 + (tid & 7) * 8);
            d[0] = make_float4(__uint_as_float((unsigned)p0), __uint_as_float((unsigned)p1),
                               __uint_as_float((unsigned)p2), __uint_as_float((unsigned)p3));
            d[1] = make_float4(__uint_as_float((unsigned)p4), __uint_as_float((unsigned)p5),
                               __uint_as_float((unsigned)p6), __uint_as_float((unsigned)p7));
        }
        __syncthreads();

        const float4* hq = (const float4*)(h_lds + k * 68);
        float acc = 0.0f;
        DOT(0) DOT(1) DOT(2) DOT(3) DOT(4) DOT(5) DOT(6) DOT(7)
        DOT(8) DOT(9) DOT(10) DOT(11) DOT(12) DOT(13) DOT(14) DOT(15)
        acc += __shfl_xor(acc, 1);
        acc += __shfl_xor(acc, 2);
        acc += __shfl_xor(acc, 4);
        if (k == 0) gsum[r] = acc + gxv;
        __syncthreads();

        if (tid < 8) {
            float gi = gsum[tid], gf = gsum[8 + tid], gg = gsum[16 + tid], go = gsum[24 + tid];
            float c2 = sigm(gf) * c_reg + sigm(gi) * tanh_fast(gg);
            float h2 = sigm(go) * tanh_fast(c2);
            c_reg = c2;
            u64 pv = ((u64)(unsigned)(t + 2) << 32) | (u64)__float_as_uint(h2);
            __hip_atomic_store(&hbuf[(size_t)(((t + 1) & 1) * 3 + chain) * HH + slice * 8 + tid],
                               pv, __ATOMIC_RELAXED, __HIP_MEMORY_SCOPE_AGENT);
            if (t + 1 < TT)
                htop[(size_t)(t + 1) * 1536 + chain * HH + slice * 8 + tid] = h2;
        }
        __syncthreads();   // protect h_lds/gsum reuse next iteration
    }
}

// ---------------------------------------------------------------------------
// per-row logits + log_softmax
__global__ __launch_bounds__(128) void k_logp(
    const float* __restrict__ summ, const float* __restrict__ Wo,
    const float* __restrict__ bo, float* __restrict__ out)
{
    __shared__ float srow[512];
    __shared__ float z[104];
    __shared__ float red[2];
    const int t = blockIdx.x, tid = threadIdx.x;
    ((float4*)srow)[tid] = ((const float4*)(summ + (size_t)t * 512))[tid];
    __syncthreads();
    if (tid < 100) {
        float a = bo[tid];
        const float* wr = Wo + (size_t)tid * 512;
        for (int k = 0; k < 512; k += 4)
            a += wr[k] * srow[k] + wr[k + 1] * srow[k + 1] + wr[k + 2] * srow[k + 2] + wr[k + 3] * srow[k + 3];
        z[tid] = a;
    }
    __syncthreads();
    if (tid < 64) {
        float m = z[tid];
        if (tid + 64 < 100) m = fmaxf(m, z[tid + 64]);
#pragma unroll
        for (int off = 32; off >= 1; off >>= 1) m = fmaxf(m, __shfl_xor(m, off, 64));
        float e = __expf(z[tid] - m) + ((tid + 64 < 100) ? __expf(z[tid + 64] - m) : 0.0f);
#pragma unroll
        for (int off = 32; off >= 1; off >>= 1) e += __shfl_xor(e, off, 64);
        if (tid == 0) { red[0] = m; red[1] = __logf(e); }
    }
    __syncthreads();
    if (tid < 100) out[(size_t)t * 100 + tid] = z[tid] - red[0] - red[1];
}

// ---------------------------------------------------------------------------
extern "C" void kernel_launch(void* const* d_in, const int* in_sizes, int n_in,
                              void* d_out, int out_size, void* d_ws, size_t ws_size,
                              hipStream_t stream)
{
    const int* words = (const int*)d_in[0];
    const int* pos   = (const int*)d_in[1];
    const int* acts  = (const int*)d_in[2];
    const float* wemb  = (const float*)d_in[3];
    const float* pemb  = (const float*)d_in[4];
    const float* aemb  = (const float*)d_in[5];
    const float* w2e_w = (const float*)d_in[6];
    const float* w2e_b = (const float*)d_in[7];
    const float* a2e_w = (const float*)d_in[8];
    const float* a2e_b = (const float*)d_in[9];
    const float* sum_w = (const float*)d_in[28];
    const float* sum_b = (const float*)d_in[29];
    const float* out_w = (const float*)d_in[30];
    const float* out_b = (const float*)d_in[31];

    float* ws = (float*)d_ws;
    float* xw   = ws;                                   // [4096*512]
    float* xa   = xw + (size_t)TT * HH;                 // [4096*512]
    float* gxp  = xa + (size_t)TT * HH;                 // [3][4096][2048]
    float* htop = gxp + (size_t)3 * TT * GG;            // [4096][1536]
    u64*   hbuf = (u64*)(htop + (size_t)TT * 3 * HH);   // [2][3][512] tagged pairs
    float* summary = xw;                                // alias: xw dead after Gx GEMMs

    hipMemsetAsync(hbuf, 0, 2 * 3 * HH * sizeof(u64), stream);

    // Phase A: input projections
    k_xw<<<dim3(TT / 8), dim3(256), 0, stream>>>(words, pos, wemb, pemb, w2e_w, w2e_b, xw);
    k_xa<<<dim3(TT / 8), dim3(256), 0, stream>>>(acts, aemb, a2e_w, a2e_b, xa);

    // Phase A: Gx[c] = x_c @ wih_c^T + (bih_c + bhh_c)
    dim3 g2(GG / 64, TT / 64);
    gemm_nt<<<g2, dim3(256), 0, stream>>>(xw, (const float*)d_in[10], gxp,
                                          (const float*)d_in[12], (const float*)d_in[13],
                                          TT, GG, HH, 0);
    gemm_nt<<<g2, dim3(256), 0, stream>>>(xw, (const float*)d_in[16], gxp + (size_t)TT * GG,
                                          (const float*)d_in[18], (const float*)d_in[19],
                                          TT, GG, HH, 0);
    gemm_nt<<<g2, dim3(256), 0, stream>>>(xa, (const float*)d_in[22], gxp + (size_t)2 * TT * GG,
                                          (const float*)d_in[24], (const float*)d_in[25],
                                          TT, GG, HH, 0);

    // Phase B: dataflow scan (192 blocks <= 256 CUs -> co-resident)
    scan_kernel<<<dim3(3 * NS), dim3(256), 0, stream>>>(
        gxp,
        (const float*)d_in[11], (const float*)d_in[17], (const float*)d_in[23],
        (const float*)d_in[14], (const float*)d_in[20], (const float*)d_in[26],
        (const float*)d_in[15], (const float*)d_in[21], (const float*)d_in[27],
        hbuf, htop);

    // Phase C: summary = tanh(Htop @ sum_w^T + sum_b); then logits + log_softmax
    dim3 g3(HH / 64, TT / 64);
    gemm_nt<<<g3, dim3(256), 0, stream>>>(htop, sum_w, summary, sum_b, nullptr,
                                          TT, HH, 3 * HH, 1);
    k_logp<<<dim3(TT), dim3(128), 0, stream>>>(summary, out_w, out_b, (float*)d_out);
}